// Round 3
// baseline (951.770 us; speedup 1.0000x reference)
//
#include <hip/hip_runtime.h>
#include <hip/hip_bf16.h>

// CGConv fused for MI355X (gfx950) — round 3: CSR two-pass, no fp32 atomics.
//   pass A: counting-sort edge ids by dst (hist -> scan -> scatter)
//   pass B: [E,256]x[256,192] bf16 MFMA GEMM + activation -> bf16 msg[E,96]
//   pass C: per-node ordered sum of msg rows via CSR, out = h + sum/deg
// Rationale: R1/R2 were stuck at ~515us with MfmaUtil 6%/VALU 21%/HBM 17% —
// the 76.8M scalar fp32 atomicAdds (L2 atomic ALU ~300-400us floor) were the
// wall. CSR eliminates them for ~100us of extra streaming traffic.

#define NODE_DIM 96
#define EDGE_DIM 64
#define IN_DIM   256
#define NT_TILES 12       // 192 output cols = 96 gates + 96 msgs
#define KT_TILES 8        // 256 / 32

typedef float  f32x4  __attribute__((ext_vector_type(4)));
typedef __bf16 bf16x8 __attribute__((ext_vector_type(8)));

__device__ __forceinline__ unsigned short bf16rne(float f) {
    unsigned int u = __float_as_uint(f);
    u += 0x7FFFu + ((u >> 16) & 1u);
    return (unsigned short)(u >> 16);
}

// ---------------------------------------------------------------------------
// Pack W_e/W_n (256x96 fp32 row-major) into bf16 MFMA B-fragment order.
// tile (kt,nt), lane l, j -> W[kt*32+(l>>4)*8+j][(nt%6)*16+(l&15)], nt<6:We else Wn
// ---------------------------------------------------------------------------
__global__ void pack_w_kernel(const float* __restrict__ We,
                              const float* __restrict__ Wn,
                              unsigned short* __restrict__ bpack) {
    int t = blockIdx.x * blockDim.x + threadIdx.x;
    if (t >= KT_TILES * NT_TILES * 64) return;
    int tile = t >> 6, lane = t & 63;
    int kt = tile / NT_TILES, nt = tile % NT_TILES;
    const float* W = (nt < 6) ? We : Wn;
    int n  = (nt % 6) * 16 + (lane & 15);
    int k0 = kt * 32 + (lane >> 4) * 8;
    union { unsigned short u[8]; uint4 v; } tmp;
#pragma unroll
    for (int j = 0; j < 8; ++j) tmp.u[j] = bf16rne(W[(k0 + j) * NODE_DIM + n]);
    *(uint4*)(bpack + (size_t)t * 8) = tmp.v;
}

// ---------------------------------------------------------------------------
// CSR build: histogram -> exclusive scan (3 kernels) -> scatter
// ---------------------------------------------------------------------------
__global__ void hist_kernel(const int* __restrict__ eidx, unsigned* __restrict__ deg, int E) {
    int e = blockIdx.x * 256 + threadIdx.x;
    if (e < E) atomicAdd(deg + eidx[E + e], 1u);
}

__device__ __forceinline__ unsigned block_excl_scan_256(unsigned v, int tid,
                                                        unsigned* wsum, unsigned* wpre,
                                                        unsigned* total) {
    int lane = tid & 63, w = tid >> 6;
    unsigned inc = v;
#pragma unroll
    for (int o = 1; o < 64; o <<= 1) {
        unsigned t = __shfl_up(inc, o, 64);
        if (lane >= o) inc += t;
    }
    if (lane == 63) wsum[w] = inc;
    __syncthreads();
    if (tid == 0) {
        unsigned s = 0;
#pragma unroll
        for (int k = 0; k < 4; ++k) { wpre[k] = s; s += wsum[k]; }
        *total = s;
    }
    __syncthreads();
    return inc - v + wpre[w];
}

__global__ void scan_block_kernel(const unsigned* __restrict__ deg,
                                  unsigned* __restrict__ scanned,
                                  unsigned* __restrict__ blocksum, int N) {
    __shared__ unsigned wsum[4], wpre[4], total;
    int tid = threadIdx.x;
    int i = blockIdx.x * 256 + tid;
    unsigned v = (i < N) ? deg[i] : 0u;
    unsigned excl = block_excl_scan_256(v, tid, wsum, wpre, &total);
    if (i < N) scanned[i] = excl;
    if (tid == 0) blocksum[blockIdx.x] = total;
}

__global__ void scan_sums_kernel(const unsigned* __restrict__ blocksum,
                                 unsigned* __restrict__ blockpref, int NB) {
    __shared__ unsigned wsum[4], wpre[4], total;
    int tid = threadIdx.x;
    unsigned v = (tid < NB) ? blocksum[tid] : 0u;
    unsigned excl = block_excl_scan_256(v, tid, wsum, wpre, &total);
    if (tid < NB) blockpref[tid] = excl;
}

__global__ void scan_finalize_kernel(const unsigned* __restrict__ scanned,
                                     const unsigned* __restrict__ blockpref,
                                     unsigned* __restrict__ offsets,
                                     unsigned* __restrict__ cursor, int N, int E) {
    int i = blockIdx.x * 256 + threadIdx.x;
    if (i < N) {
        unsigned o = scanned[i] + blockpref[i >> 8];
        offsets[i] = o;
        cursor[i]  = o;
    }
    if (i == 0) offsets[N] = (unsigned)E;
}

__global__ void scatter_kernel(const int* __restrict__ eidx,
                               unsigned* __restrict__ cursor,
                               unsigned* __restrict__ sorted, int E) {
    int e = blockIdx.x * 256 + threadIdx.x;
    if (e < E) {
        int d = eidx[E + e];
        unsigned pos = atomicAdd(cursor + d, 1u);
        sorted[pos] = (unsigned)e;
    }
}

// ---------------------------------------------------------------------------
// Pass B: per-edge GEMM + activation -> bf16 msg[E, 96]. No LDS, no atomics.
// Block = 256 thr = 4 waves; wave handles 32 edges (2 row-tiles of 16).
// ---------------------------------------------------------------------------
__global__ __launch_bounds__(256)
void gemm_msg_kernel(const float* __restrict__ h,
                     const int*   __restrict__ eidx,
                     const float* __restrict__ ea,
                     const unsigned short* __restrict__ bpack,
                     const float* __restrict__ be,
                     const float* __restrict__ bn,
                     unsigned short* __restrict__ msg,
                     int E) {
    const int tid  = threadIdx.x;
    const int wave = tid >> 6, lane = tid & 63;
    const int m    = lane & 15;
    const int quad = lane >> 4;
    const int base = blockIdx.x * 128 + wave * 32;

    const float* hs[2]; const float* hd[2]; const float* ep[2];
#pragma unroll
    for (int mt = 0; mt < 2; ++mt) {
        int e  = base + mt * 16 + m;
        int eg = (e < E) ? e : (E - 1);
        int src = eidx[eg];
        int dst = eidx[E + eg];
        hs[mt] = h  + (size_t)src * NODE_DIM;
        hd[mt] = h  + (size_t)dst * NODE_DIM;
        ep[mt] = ea + (size_t)eg  * EDGE_DIM;
    }

    f32x4 acc[2][NT_TILES];
#pragma unroll
    for (int mt = 0; mt < 2; ++mt)
#pragma unroll
        for (int nt = 0; nt < NT_TILES; ++nt) acc[mt][nt] = (f32x4){0.f, 0.f, 0.f, 0.f};

#pragma unroll
    for (int kt = 0; kt < KT_TILES; ++kt) {
        const int ko = kt * 32 + quad * 8;
        bf16x8 A[2];
#pragma unroll
        for (int mt = 0; mt < 2; ++mt) {
            const float* p;
            if (kt < 3)      p = hs[mt] + ko;
            else if (kt < 6) p = hd[mt] + (ko - NODE_DIM);
            else             p = ep[mt] + (ko - 2 * NODE_DIM);
            const float4 v0 = *(const float4*)p;
            const float4 v1 = *(const float4*)(p + 4);
            union { unsigned short u[8]; bf16x8 b; } t;
            t.u[0] = bf16rne(v0.x); t.u[1] = bf16rne(v0.y);
            t.u[2] = bf16rne(v0.z); t.u[3] = bf16rne(v0.w);
            t.u[4] = bf16rne(v1.x); t.u[5] = bf16rne(v1.y);
            t.u[6] = bf16rne(v1.z); t.u[7] = bf16rne(v1.w);
            A[mt] = t.b;
        }
#pragma unroll
        for (int nt = 0; nt < NT_TILES; ++nt) {
            bf16x8 bfrag = *(const bf16x8*)(bpack +
                             (size_t)((kt * NT_TILES + nt) * 64 + lane) * 8);
#pragma unroll
            for (int mt = 0; mt < 2; ++mt)
                acc[mt][nt] = __builtin_amdgcn_mfma_f32_16x16x32_bf16(A[mt], bfrag, acc[mt][nt], 0, 0, 0);
        }
    }

    // epilogue: C layout col = nt*16 + (lane&15), row-in-tile = quad*4 + r
#pragma unroll
    for (int nt = 0; nt < 6; ++nt) {
        const int col = nt * 16 + m;
        const float bev = be[col];
        const float bnv = bn[col];
#pragma unroll
        for (int mt = 0; mt < 2; ++mt) {
#pragma unroll
            for (int r = 0; r < 4; ++r) {
                const int e = base + mt * 16 + quad * 4 + r;
                if (e >= E) continue;
                float g  = acc[mt][nt][r] + bev;
                float mm = acc[mt][nt + 6][r] + bnv;
                float gate = 1.0f / (1.0f + __expf(-g));
                float sp   = fmaxf(mm, 0.0f) + __logf(1.0f + __expf(-fabsf(mm)));
                msg[(size_t)e * NODE_DIM + col] = bf16rne(gate * sp);
            }
        }
    }
}

// ---------------------------------------------------------------------------
// Pass C: per-node CSR reduce. Block 256 = 2 nodes; threads 0..95 of each
// half cover the 96 cols. eid fetch pipelined one ahead of the msg read.
// ---------------------------------------------------------------------------
__global__ __launch_bounds__(256)
void aggregate_kernel(const float* __restrict__ h,
                      const unsigned* __restrict__ offsets,
                      const unsigned* __restrict__ sorted,
                      const unsigned short* __restrict__ msg,
                      float* __restrict__ out, int N) {
    const int half = threadIdx.x >> 7;        // 0 or 1
    const int col  = threadIdx.x & 127;
    const int n    = blockIdx.x * 2 + half;
    if (n >= N || col >= NODE_DIM) return;

    const unsigned o0 = offsets[n];
    const unsigned o1 = offsets[n + 1];
    const int deg = (int)(o1 - o0);

    float sum = 0.f;
    unsigned ecur = (deg > 0) ? sorted[o0] : 0u;
    for (int k = 0; k < deg; ++k) {
        unsigned enext = (k + 1 < deg) ? sorted[o0 + k + 1] : ecur;
        unsigned short u = msg[(size_t)ecur * NODE_DIM + col];
        sum += __uint_as_float(((unsigned)u) << 16);
        ecur = enext;
    }
    float c = (deg > 0) ? (float)deg : 1.f;
    out[(size_t)n * NODE_DIM + col] = h[(size_t)n * NODE_DIM + col] + sum / c;
}

// ---------------------------------------------------------------------------
// Fallback (R2 path) if workspace is too small for the CSR pipeline.
// ---------------------------------------------------------------------------
#define TILE_E 64
__global__ __launch_bounds__(256, 4)
void cgconv_atomic_kernel(const float* __restrict__ h,
                          const int*   __restrict__ eidx,
                          const float* __restrict__ ea,
                          const unsigned short* __restrict__ bpack,
                          const float* __restrict__ be,
                          const float* __restrict__ bn,
                          float* __restrict__ hnew,
                          float* __restrict__ cnt,
                          int E) {
    const int tid  = threadIdx.x;
    const int wave = tid >> 6, lane = tid & 63;
    const int m    = lane & 15;
    const int quad = lane >> 4;

    const int e  = blockIdx.x * TILE_E + wave * 16 + m;
    const int eg = (e < E) ? e : (E - 1);
    const int src = eidx[eg];
    const int dst = eidx[E + eg];
    if (quad == 0 && e < E) unsafeAtomicAdd(cnt + dst, 1.0f);

    f32x4 acc[NT_TILES];
#pragma unroll
    for (int nt = 0; nt < NT_TILES; ++nt) acc[nt] = (f32x4){0.f, 0.f, 0.f, 0.f};

    const float* hsrc = h + (size_t)src * NODE_DIM;
    const float* hdst = h + (size_t)dst * NODE_DIM;
    const float* earo = ea + (size_t)eg * EDGE_DIM;

#pragma unroll
    for (int kt = 0; kt < KT_TILES; ++kt) {
        const int ko = kt * 32 + quad * 8;
        const float* p;
        if (kt < 3)      p = hsrc + ko;
        else if (kt < 6) p = hdst + (ko - NODE_DIM);
        else             p = earo + (ko - 2 * NODE_DIM);
        const float4 v0 = *(const float4*)p;
        const float4 v1 = *(const float4*)(p + 4);
        union { unsigned short u[8]; bf16x8 b; } A;
        A.u[0] = bf16rne(v0.x); A.u[1] = bf16rne(v0.y);
        A.u[2] = bf16rne(v0.z); A.u[3] = bf16rne(v0.w);
        A.u[4] = bf16rne(v1.x); A.u[5] = bf16rne(v1.y);
        A.u[6] = bf16rne(v1.z); A.u[7] = bf16rne(v1.w);
#pragma unroll
        for (int nt = 0; nt < NT_TILES; ++nt) {
            bf16x8 bfrag = *(const bf16x8*)(bpack +
                             (size_t)((kt * NT_TILES + nt) * 64 + lane) * 8);
            acc[nt] = __builtin_amdgcn_mfma_f32_16x16x32_bf16(A.b, bfrag, acc[nt], 0, 0, 0);
        }
    }

    int drow[4], erow[4];
#pragma unroll
    for (int r = 0; r < 4; ++r) {
        drow[r] = __shfl(dst, quad * 4 + r, 64);
        erow[r] = blockIdx.x * TILE_E + wave * 16 + quad * 4 + r;
    }
#pragma unroll
    for (int nt = 0; nt < 6; ++nt) {
        const int col = nt * 16 + m;
        const float bev = be[col];
        const float bnv = bn[col];
#pragma unroll
        for (int r = 0; r < 4; ++r) {
            if (erow[r] >= E) continue;
            float g  = acc[nt][r] + bev;
            float mm = acc[nt + 6][r] + bnv;
            float gate = 1.0f / (1.0f + __expf(-g));
            float sp   = fmaxf(mm, 0.0f) + __logf(1.0f + __expf(-fabsf(mm)));
            unsafeAtomicAdd(hnew + (size_t)drow[r] * NODE_DIM + col, gate * sp);
        }
    }
}

__global__ void finalize_kernel(const float* __restrict__ h,
                                const float* __restrict__ hnew,
                                const float* __restrict__ cnt,
                                float* __restrict__ out,
                                int total4) {
    int i = blockIdx.x * blockDim.x + threadIdx.x;
    if (i >= total4) return;
    int n = i / 24;
    float inv = 1.0f / fmaxf(cnt[n], 1.0f);
    float4 hv = ((const float4*)h)[i];
    float4 av = ((const float4*)hnew)[i];
    float4 o = {hv.x + av.x * inv, hv.y + av.y * inv, hv.z + av.z * inv, hv.w + av.w * inv};
    ((float4*)out)[i] = o;
}

// ---------------------------------------------------------------------------
extern "C" void kernel_launch(void* const* d_in, const int* in_sizes, int n_in,
                              void* d_out, int out_size, void* d_ws, size_t ws_size,
                              hipStream_t stream) {
    const float* h   = (const float*)d_in[0];
    const int*   ei  = (const int*)  d_in[1];
    const float* ea  = (const float*)d_in[2];
    const float* We  = (const float*)d_in[3];
    const float* be  = (const float*)d_in[4];
    const float* Wn  = (const float*)d_in[5];
    const float* bn  = (const float*)d_in[6];

    const int N = in_sizes[0] / NODE_DIM;     // 50000
    const int E = in_sizes[2] / EDGE_DIM;     // 800000
    char* ws = (char*)d_ws;

    // ---- workspace layout ----
    size_t off = 0;
    auto take = [&](size_t bytes) { size_t o = off; off = (off + bytes + 511) & ~(size_t)511; return o; };
    const size_t O_BPACK  = take((size_t)KT_TILES * NT_TILES * 64 * 16);   // 96 KB
    const size_t O_DEG    = take((size_t)N * 4);
    const size_t O_SCAN   = take((size_t)N * 4);
    const size_t O_BSUM   = take(1024);
    const size_t O_BPREF  = take(1024);
    const size_t O_OFFS   = take((size_t)(N + 1) * 4);
    const size_t O_CURS   = take((size_t)N * 4);
    const size_t O_SORTED = take((size_t)E * 4);
    const size_t O_MSG    = take((size_t)E * NODE_DIM * 2);               // 153.6 MB
    const size_t NEED = off;

    unsigned short* bpack = (unsigned short*)(ws + O_BPACK);
    pack_w_kernel<<<(KT_TILES * NT_TILES * 64 + 255) / 256, 256, 0, stream>>>(We, Wn, bpack);

    if (ws_size >= NEED) {
        // ================= CSR two-pass path =================
        unsigned* deg    = (unsigned*)(ws + O_DEG);
        unsigned* scn    = (unsigned*)(ws + O_SCAN);
        unsigned* bsum   = (unsigned*)(ws + O_BSUM);
        unsigned* bpref  = (unsigned*)(ws + O_BPREF);
        unsigned* offs   = (unsigned*)(ws + O_OFFS);
        unsigned* curs   = (unsigned*)(ws + O_CURS);
        unsigned* sorted = (unsigned*)(ws + O_SORTED);
        unsigned short* msg = (unsigned short*)(ws + O_MSG);

        hipMemsetAsync(deg, 0, (size_t)N * 4, stream);

        const int NB = (N + 255) / 256;   // 196 (fits one scan_sums block)
        hist_kernel<<<(E + 255) / 256, 256, 0, stream>>>(ei, deg, E);
        scan_block_kernel<<<NB, 256, 0, stream>>>(deg, scn, bsum, N);
        scan_sums_kernel<<<1, 256, 0, stream>>>(bsum, bpref, NB);
        scan_finalize_kernel<<<NB, 256, 0, stream>>>(scn, bpref, offs, curs, N, E);
        scatter_kernel<<<(E + 255) / 256, 256, 0, stream>>>(ei, curs, sorted, E);

        gemm_msg_kernel<<<(E + 127) / 128, 256, 0, stream>>>(h, ei, ea, bpack, be, bn, msg, E);

        aggregate_kernel<<<(N + 1) / 2, 256, 0, stream>>>(h, offs, sorted, msg, (float*)d_out, N);
    } else {
        // ================= fallback: R2 atomic path =================
        size_t cnt_off  = O_DEG;                       // reuse layout region
        size_t hnew_off = (cnt_off + (size_t)N * 4 + 511) & ~(size_t)511;
        float* cnt  = (float*)(ws + cnt_off);
        float* hnew = (float*)(ws + hnew_off);
        hipMemsetAsync(ws + cnt_off, 0, hnew_off - cnt_off + (size_t)N * NODE_DIM * 4, stream);
        cgconv_atomic_kernel<<<(E + TILE_E - 1) / TILE_E, 256, 0, stream>>>(
            h, ei, ea, bpack, be, bn, hnew, cnt, E);
        const int total4 = N * (NODE_DIM / 4);
        finalize_kernel<<<(total4 + 255) / 256, 256, 0, stream>>>(h, hnew, cnt, (float*)d_out, total4);
    }
}

// Round 4
// 773.838 us; speedup vs baseline: 1.2299x; 1.2299x over previous
//
#include <hip/hip_runtime.h>
#include <hip/hip_bf16.h>

// CGConv fused for MI355X (gfx950) — round 4: latency-lean GEMM.
//   pre: pack W into MFMA-B order; convert h -> bf16 once (hb).
//   pass A: counting-sort edge ids by dst (hist -> scan -> scatter)
//   pass B: per-edge bf16 MFMA GEMM + activation -> bf16 msg[E,96]
//           A-fragment = ONE dwordx4 per k-tile off a row pointer (imm offset),
//           all h-gathers hoisted & in flight together, zero h-convert VALU.
//   pass C: per-node ordered CSR sum, out = h + sum/deg
// R1-R3 all sat at ~515us (MfmaUtil 6%, VALU 22%, HBM 13-17%) regardless of
// staging/atomics => latency-bound on the gather+convert critical path with
// ~2 waves/SIMD (92 VGPR + 96 AGPR). This round: minimize per-wave serial
// latency and VALU, raise residency (48-AGPR acc).

#define NODE_DIM 96
#define EDGE_DIM 64
#define IN_DIM   256
#define NT_TILES 12       // 192 output cols = 96 gates + 96 msgs
#define KT_TILES 8        // 256 / 32

typedef float  f32x4  __attribute__((ext_vector_type(4)));
typedef __bf16 bf16x8 __attribute__((ext_vector_type(8)));

__device__ __forceinline__ unsigned short bf16rne(float f) {
    unsigned int u = __float_as_uint(f);
    u += 0x7FFFu + ((u >> 16) & 1u);
    return (unsigned short)(u >> 16);
}

// ---------------------------------------------------------------------------
// Pack W_e/W_n (256x96 fp32 row-major) into bf16 MFMA B-fragment order.
// ---------------------------------------------------------------------------
__global__ void pack_w_kernel(const float* __restrict__ We,
                              const float* __restrict__ Wn,
                              unsigned short* __restrict__ bpack) {
    int t = blockIdx.x * blockDim.x + threadIdx.x;
    if (t >= KT_TILES * NT_TILES * 64) return;
    int tile = t >> 6, lane = t & 63;
    int kt = tile / NT_TILES, nt = tile % NT_TILES;
    const float* W = (nt < 6) ? We : Wn;
    int n  = (nt % 6) * 16 + (lane & 15);
    int k0 = kt * 32 + (lane >> 4) * 8;
    union { unsigned short u[8]; uint4 v; } tmp;
#pragma unroll
    for (int j = 0; j < 8; ++j) tmp.u[j] = bf16rne(W[(k0 + j) * NODE_DIM + n]);
    *(uint4*)(bpack + (size_t)t * 8) = tmp.v;
}

// ---------------------------------------------------------------------------
// h (N x 96 fp32) -> hb (N x 96 bf16), one 16B store per thread.
// ---------------------------------------------------------------------------
__global__ void cvt_h_kernel(const float* __restrict__ h,
                             unsigned short* __restrict__ hb, int total8) {
    int i = blockIdx.x * 256 + threadIdx.x;     // handles 8 floats
    if (i >= total8) return;
    const float4 v0 = ((const float4*)h)[i * 2];
    const float4 v1 = ((const float4*)h)[i * 2 + 1];
    union { unsigned short u[8]; uint4 v; } p;
    p.u[0] = bf16rne(v0.x); p.u[1] = bf16rne(v0.y);
    p.u[2] = bf16rne(v0.z); p.u[3] = bf16rne(v0.w);
    p.u[4] = bf16rne(v1.x); p.u[5] = bf16rne(v1.y);
    p.u[6] = bf16rne(v1.z); p.u[7] = bf16rne(v1.w);
    ((uint4*)hb)[i] = p.v;
}

// ---------------------------------------------------------------------------
// CSR build: histogram -> exclusive scan -> scatter
// ---------------------------------------------------------------------------
__global__ void hist_kernel(const int* __restrict__ eidx, unsigned* __restrict__ deg, int E) {
    int e = blockIdx.x * 256 + threadIdx.x;
    if (e < E) atomicAdd(deg + eidx[E + e], 1u);
}

__device__ __forceinline__ unsigned block_excl_scan_256(unsigned v, int tid,
                                                        unsigned* wsum, unsigned* wpre,
                                                        unsigned* total) {
    int lane = tid & 63, w = tid >> 6;
    unsigned inc = v;
#pragma unroll
    for (int o = 1; o < 64; o <<= 1) {
        unsigned t = __shfl_up(inc, o, 64);
        if (lane >= o) inc += t;
    }
    if (lane == 63) wsum[w] = inc;
    __syncthreads();
    if (tid == 0) {
        unsigned s = 0;
#pragma unroll
        for (int k = 0; k < 4; ++k) { wpre[k] = s; s += wsum[k]; }
        *total = s;
    }
    __syncthreads();
    return inc - v + wpre[w];
}

__global__ void scan_block_kernel(const unsigned* __restrict__ deg,
                                  unsigned* __restrict__ scanned,
                                  unsigned* __restrict__ blocksum, int N) {
    __shared__ unsigned wsum[4], wpre[4], total;
    int tid = threadIdx.x;
    int i = blockIdx.x * 256 + tid;
    unsigned v = (i < N) ? deg[i] : 0u;
    unsigned excl = block_excl_scan_256(v, tid, wsum, wpre, &total);
    if (i < N) scanned[i] = excl;
    if (tid == 0) blocksum[blockIdx.x] = total;
}

__global__ void scan_sums_kernel(const unsigned* __restrict__ blocksum,
                                 unsigned* __restrict__ blockpref, int NB) {
    __shared__ unsigned wsum[4], wpre[4], total;
    int tid = threadIdx.x;
    unsigned v = (tid < NB) ? blocksum[tid] : 0u;
    unsigned excl = block_excl_scan_256(v, tid, wsum, wpre, &total);
    if (tid < NB) blockpref[tid] = excl;
}

__global__ void scan_finalize_kernel(const unsigned* __restrict__ scanned,
                                     const unsigned* __restrict__ blockpref,
                                     unsigned* __restrict__ offsets,
                                     unsigned* __restrict__ cursor, int N, int E) {
    int i = blockIdx.x * 256 + threadIdx.x;
    if (i < N) {
        unsigned o = scanned[i] + blockpref[i >> 8];
        offsets[i] = o;
        cursor[i]  = o;
    }
    if (i == 0) offsets[N] = (unsigned)E;
}

__global__ void scatter_kernel(const int* __restrict__ eidx,
                               unsigned* __restrict__ cursor,
                               unsigned* __restrict__ sorted, int E) {
    int e = blockIdx.x * 256 + threadIdx.x;
    if (e < E) {
        int d = eidx[E + e];
        unsigned pos = atomicAdd(cursor + d, 1u);
        sorted[pos] = (unsigned)e;
    }
}

// ---------------------------------------------------------------------------
// Pass B: per-edge GEMM + activation -> bf16 msg[E, 96].
// Block = 256 = 4 waves; wave handles 16 edges. No LDS, no barriers.
// ---------------------------------------------------------------------------
__global__ __launch_bounds__(256)
void gemm_msg_kernel(const unsigned short* __restrict__ hb,
                     const int*   __restrict__ eidx,
                     const float* __restrict__ ea,
                     const unsigned short* __restrict__ bpack,
                     const float* __restrict__ be,
                     const float* __restrict__ bn,
                     unsigned short* __restrict__ msg,
                     int E) {
    const int tid  = threadIdx.x;
    const int wave = tid >> 6, lane = tid & 63;
    const int m    = lane & 15;
    const int quad = lane >> 4;

    const int e  = blockIdx.x * 64 + wave * 16 + m;
    const int eg = (e < E) ? e : (E - 1);
    const int src = eidx[eg];
    const int dst = eidx[E + eg];

    // row pointers; all in-row accesses use compile-time immediate offsets
    const unsigned short* hsq = hb + (size_t)src * NODE_DIM + quad * 8;
    const unsigned short* hdq = hb + (size_t)dst * NODE_DIM + quad * 8;
    const float*          epq = ea + (size_t)eg  * EDGE_DIM + quad * 8;
    const unsigned short* bl  = bpack + lane * 8;

    // hoist ALL gathers: 6 bf16x8 for h (one per k-tile) + 4 float4 for ea
    bf16x8 Ah[6];
#pragma unroll
    for (int kt = 0; kt < 3; ++kt) Ah[kt]     = *(const bf16x8*)(hsq + kt * 32);
#pragma unroll
    for (int kt = 0; kt < 3; ++kt) Ah[3 + kt] = *(const bf16x8*)(hdq + kt * 32);
    float4 er0 = *(const float4*)(epq);
    float4 er1 = *(const float4*)(epq + 4);
    float4 er2 = *(const float4*)(epq + 32);
    float4 er3 = *(const float4*)(epq + 36);

    f32x4 acc[NT_TILES];
#pragma unroll
    for (int nt = 0; nt < NT_TILES; ++nt) acc[nt] = (f32x4){0.f, 0.f, 0.f, 0.f};

#pragma unroll
    for (int kt = 0; kt < KT_TILES; ++kt) {
        bf16x8 a;
        if (kt < 6) {
            a = Ah[kt];
        } else {
            const float4 v0 = (kt == 6) ? er0 : er2;
            const float4 v1 = (kt == 6) ? er1 : er3;
            union { unsigned short u[8]; bf16x8 b; } t;
            t.u[0] = bf16rne(v0.x); t.u[1] = bf16rne(v0.y);
            t.u[2] = bf16rne(v0.z); t.u[3] = bf16rne(v0.w);
            t.u[4] = bf16rne(v1.x); t.u[5] = bf16rne(v1.y);
            t.u[6] = bf16rne(v1.z); t.u[7] = bf16rne(v1.w);
            a = t.b;
        }
#pragma unroll
        for (int nt = 0; nt < NT_TILES; ++nt) {
            bf16x8 bfrag = *(const bf16x8*)(bl + (kt * NT_TILES + nt) * 512);
            acc[nt] = __builtin_amdgcn_mfma_f32_16x16x32_bf16(a, bfrag, acc[nt], 0, 0, 0);
        }
    }

    // epilogue: C layout col = nt*16 + m, row-in-tile = quad*4 + r
#pragma unroll
    for (int nt = 0; nt < 6; ++nt) {
        const int col = nt * 16 + m;
        const float bev = be[col];
        const float bnv = bn[col];
#pragma unroll
        for (int r = 0; r < 4; ++r) {
            const int ee = blockIdx.x * 64 + wave * 16 + quad * 4 + r;
            if (ee >= E) continue;
            float g  = acc[nt][r] + bev;
            float mm = acc[nt + 6][r] + bnv;
            float gate = 1.0f / (1.0f + __expf(-g));
            float sp   = fmaxf(mm, 0.0f) + __logf(1.0f + __expf(-fabsf(mm)));
            msg[(size_t)ee * NODE_DIM + col] = bf16rne(gate * sp);
        }
    }
}

// ---------------------------------------------------------------------------
// Pass C: per-node CSR reduce. Block 256 = 2 nodes x 128 threads.
// ---------------------------------------------------------------------------
__global__ __launch_bounds__(256)
void aggregate_kernel(const float* __restrict__ h,
                      const unsigned* __restrict__ offsets,
                      const unsigned* __restrict__ sorted,
                      const unsigned short* __restrict__ msg,
                      float* __restrict__ out, int N) {
    const int half = threadIdx.x >> 7;
    const int col  = threadIdx.x & 127;
    const int n    = blockIdx.x * 2 + half;
    if (n >= N || col >= NODE_DIM) return;

    const unsigned o0 = offsets[n];
    const unsigned o1 = offsets[n + 1];
    const int deg = (int)(o1 - o0);

    float sum = 0.f;
    unsigned ecur = (deg > 0) ? sorted[o0] : 0u;
    for (int k = 0; k < deg; ++k) {
        unsigned enext = (k + 1 < deg) ? sorted[o0 + k + 1] : ecur;
        unsigned short u = msg[(size_t)ecur * NODE_DIM + col];
        sum += __uint_as_float(((unsigned)u) << 16);
        ecur = enext;
    }
    float c = (deg > 0) ? (float)deg : 1.f;
    out[(size_t)n * NODE_DIM + col] = h[(size_t)n * NODE_DIM + col] + sum / c;
}

// ---------------------------------------------------------------------------
// Fallback (atomic path) if workspace is too small for the CSR pipeline.
// ---------------------------------------------------------------------------
#define TILE_E 64
__global__ __launch_bounds__(256, 4)
void cgconv_atomic_kernel(const float* __restrict__ h,
                          const int*   __restrict__ eidx,
                          const float* __restrict__ ea,
                          const unsigned short* __restrict__ bpack,
                          const float* __restrict__ be,
                          const float* __restrict__ bn,
                          float* __restrict__ hnew,
                          float* __restrict__ cnt,
                          int E) {
    const int tid  = threadIdx.x;
    const int wave = tid >> 6, lane = tid & 63;
    const int m    = lane & 15;
    const int quad = lane >> 4;

    const int e  = blockIdx.x * TILE_E + wave * 16 + m;
    const int eg = (e < E) ? e : (E - 1);
    const int src = eidx[eg];
    const int dst = eidx[E + eg];
    if (quad == 0 && e < E) unsafeAtomicAdd(cnt + dst, 1.0f);

    f32x4 acc[NT_TILES];
#pragma unroll
    for (int nt = 0; nt < NT_TILES; ++nt) acc[nt] = (f32x4){0.f, 0.f, 0.f, 0.f};

    const float* hsrc = h + (size_t)src * NODE_DIM;
    const float* hdst = h + (size_t)dst * NODE_DIM;
    const float* earo = ea + (size_t)eg * EDGE_DIM;

#pragma unroll
    for (int kt = 0; kt < KT_TILES; ++kt) {
        const int ko = kt * 32 + quad * 8;
        const float* p;
        if (kt < 3)      p = hsrc + ko;
        else if (kt < 6) p = hdst + (ko - NODE_DIM);
        else             p = earo + (ko - 2 * NODE_DIM);
        const float4 v0 = *(const float4*)p;
        const float4 v1 = *(const float4*)(p + 4);
        union { unsigned short u[8]; bf16x8 b; } A;
        A.u[0] = bf16rne(v0.x); A.u[1] = bf16rne(v0.y);
        A.u[2] = bf16rne(v0.z); A.u[3] = bf16rne(v0.w);
        A.u[4] = bf16rne(v1.x); A.u[5] = bf16rne(v1.y);
        A.u[6] = bf16rne(v1.z); A.u[7] = bf16rne(v1.w);
#pragma unroll
        for (int nt = 0; nt < NT_TILES; ++nt) {
            bf16x8 bfrag = *(const bf16x8*)(bpack +
                             (size_t)((kt * NT_TILES + nt) * 64 + lane) * 8);
            acc[nt] = __builtin_amdgcn_mfma_f32_16x16x32_bf16(A.b, bfrag, acc[nt], 0, 0, 0);
        }
    }

    int drow[4], erow[4];
#pragma unroll
    for (int r = 0; r < 4; ++r) {
        drow[r] = __shfl(dst, quad * 4 + r, 64);
        erow[r] = blockIdx.x * TILE_E + wave * 16 + quad * 4 + r;
    }
#pragma unroll
    for (int nt = 0; nt < 6; ++nt) {
        const int col = nt * 16 + m;
        const float bev = be[col];
        const float bnv = bn[col];
#pragma unroll
        for (int r = 0; r < 4; ++r) {
            if (erow[r] >= E) continue;
            float g  = acc[nt][r] + bev;
            float mm = acc[nt + 6][r] + bnv;
            float gate = 1.0f / (1.0f + __expf(-g));
            float sp   = fmaxf(mm, 0.0f) + __logf(1.0f + __expf(-fabsf(mm)));
            unsafeAtomicAdd(hnew + (size_t)drow[r] * NODE_DIM + col, gate * sp);
        }
    }
}

__global__ void finalize_kernel(const float* __restrict__ h,
                                const float* __restrict__ hnew,
                                const float* __restrict__ cnt,
                                float* __restrict__ out,
                                int total4) {
    int i = blockIdx.x * blockDim.x + threadIdx.x;
    if (i >= total4) return;
    int n = i / 24;
    float inv = 1.0f / fmaxf(cnt[n], 1.0f);
    float4 hv = ((const float4*)h)[i];
    float4 av = ((const float4*)hnew)[i];
    float4 o = {hv.x + av.x * inv, hv.y + av.y * inv, hv.z + av.z * inv, hv.w + av.w * inv};
    ((float4*)out)[i] = o;
}

// ---------------------------------------------------------------------------
extern "C" void kernel_launch(void* const* d_in, const int* in_sizes, int n_in,
                              void* d_out, int out_size, void* d_ws, size_t ws_size,
                              hipStream_t stream) {
    const float* h   = (const float*)d_in[0];
    const int*   ei  = (const int*)  d_in[1];
    const float* ea  = (const float*)d_in[2];
    const float* We  = (const float*)d_in[3];
    const float* be  = (const float*)d_in[4];
    const float* Wn  = (const float*)d_in[5];
    const float* bn  = (const float*)d_in[6];

    const int N = in_sizes[0] / NODE_DIM;     // 50000
    const int E = in_sizes[2] / EDGE_DIM;     // 800000
    char* ws = (char*)d_ws;

    size_t off = 0;
    auto take = [&](size_t bytes) { size_t o = off; off = (off + bytes + 511) & ~(size_t)511; return o; };
    const size_t O_BPACK  = take((size_t)KT_TILES * NT_TILES * 64 * 16);   // 96 KB
    const size_t O_DEG    = take((size_t)N * 4);
    const size_t O_SCAN   = take((size_t)N * 4);
    const size_t O_BSUM   = take(1024);
    const size_t O_BPREF  = take(1024);
    const size_t O_OFFS   = take((size_t)(N + 1) * 4);
    const size_t O_CURS   = take((size_t)N * 4);
    const size_t O_SORTED = take((size_t)E * 4);
    const size_t O_HB     = take((size_t)N * NODE_DIM * 2);               // 9.6 MB
    const size_t O_MSG    = take((size_t)E * NODE_DIM * 2);               // 153.6 MB
    const size_t NEED = off;

    unsigned short* bpack = (unsigned short*)(ws + O_BPACK);
    pack_w_kernel<<<(KT_TILES * NT_TILES * 64 + 255) / 256, 256, 0, stream>>>(We, Wn, bpack);

    if (ws_size >= NEED) {
        unsigned* deg    = (unsigned*)(ws + O_DEG);
        unsigned* scn    = (unsigned*)(ws + O_SCAN);
        unsigned* bsum   = (unsigned*)(ws + O_BSUM);
        unsigned* bpref  = (unsigned*)(ws + O_BPREF);
        unsigned* offs   = (unsigned*)(ws + O_OFFS);
        unsigned* curs   = (unsigned*)(ws + O_CURS);
        unsigned* sorted = (unsigned*)(ws + O_SORTED);
        unsigned short* hb  = (unsigned short*)(ws + O_HB);
        unsigned short* msg = (unsigned short*)(ws + O_MSG);

        hipMemsetAsync(deg, 0, (size_t)N * 4, stream);

        const int total8 = N * NODE_DIM / 8;   // 600000
        cvt_h_kernel<<<(total8 + 255) / 256, 256, 0, stream>>>(h, hb, total8);

        const int NB = (N + 255) / 256;
        hist_kernel<<<(E + 255) / 256, 256, 0, stream>>>(ei, deg, E);
        scan_block_kernel<<<NB, 256, 0, stream>>>(deg, scn, bsum, N);
        scan_sums_kernel<<<1, 256, 0, stream>>>(bsum, bpref, NB);
        scan_finalize_kernel<<<NB, 256, 0, stream>>>(scn, bpref, offs, curs, N, E);
        scatter_kernel<<<(E + 255) / 256, 256, 0, stream>>>(ei, curs, sorted, E);

        gemm_msg_kernel<<<(E + 63) / 64, 256, 0, stream>>>(hb, ei, ea, bpack, be, bn, msg, E);

        aggregate_kernel<<<(N + 1) / 2, 256, 0, stream>>>(h, offs, sorted, msg, (float*)d_out, N);
    } else {
        size_t cnt_off  = O_DEG;
        size_t hnew_off = (cnt_off + (size_t)N * 4 + 511) & ~(size_t)511;
        float* cnt  = (float*)(ws + cnt_off);
        float* hnew = (float*)(ws + hnew_off);
        hipMemsetAsync(ws + cnt_off, 0, hnew_off - cnt_off + (size_t)N * NODE_DIM * 4, stream);
        cgconv_atomic_kernel<<<(E + TILE_E - 1) / TILE_E, 256, 0, stream>>>(
            h, ei, ea, bpack, be, bn, hnew, cnt, E);
        const int total4 = N * (NODE_DIM / 4);
        finalize_kernel<<<(total4 + 255) / 256, 256, 0, stream>>>(h, hnew, cnt, (float*)d_out, total4);
    }
}

// Round 5
// 632.183 us; speedup vs baseline: 1.5055x; 1.2241x over previous
//
#include <hip/hip_runtime.h>
#include <hip/hip_bf16.h>

// CGConv fused for MI355X (gfx950) — round 5.
//   gemm: mt=2 (32 edges/wave) to halve B-table L2 traffic; in-loop A loads,
//         __launch_bounds__(256,3) to keep >=3 waves/SIMD.
//   CSR:  scatter produces inverse-perm rank[e]; gemm writes msg rows directly
//         at CSR position -> aggregate is a contiguous vectorized stream.

#define NODE_DIM 96
#define EDGE_DIM 64
#define IN_DIM   256
#define NT_TILES 12       // 192 output cols = 96 gates + 96 msgs
#define KT_TILES 8        // 256 / 32

typedef float  f32x4  __attribute__((ext_vector_type(4)));
typedef __bf16 bf16x8 __attribute__((ext_vector_type(8)));

__device__ __forceinline__ unsigned short bf16rne(float f) {
    unsigned int u = __float_as_uint(f);
    u += 0x7FFFu + ((u >> 16) & 1u);
    return (unsigned short)(u >> 16);
}

// ---------------------------------------------------------------------------
// Pack W_e/W_n (256x96 fp32 row-major) into bf16 MFMA B-fragment order.
// ---------------------------------------------------------------------------
__global__ void pack_w_kernel(const float* __restrict__ We,
                              const float* __restrict__ Wn,
                              unsigned short* __restrict__ bpack) {
    int t = blockIdx.x * blockDim.x + threadIdx.x;
    if (t >= KT_TILES * NT_TILES * 64) return;
    int tile = t >> 6, lane = t & 63;
    int kt = tile / NT_TILES, nt = tile % NT_TILES;
    const float* W = (nt < 6) ? We : Wn;
    int n  = (nt % 6) * 16 + (lane & 15);
    int k0 = kt * 32 + (lane >> 4) * 8;
    union { unsigned short u[8]; uint4 v; } tmp;
#pragma unroll
    for (int j = 0; j < 8; ++j) tmp.u[j] = bf16rne(W[(k0 + j) * NODE_DIM + n]);
    *(uint4*)(bpack + (size_t)t * 8) = tmp.v;
}

// ---------------------------------------------------------------------------
// h (N x 96 fp32) -> hb (N x 96 bf16)
// ---------------------------------------------------------------------------
__global__ void cvt_h_kernel(const float* __restrict__ h,
                             unsigned short* __restrict__ hb, int total8) {
    int i = blockIdx.x * 256 + threadIdx.x;
    if (i >= total8) return;
    const float4 v0 = ((const float4*)h)[i * 2];
    const float4 v1 = ((const float4*)h)[i * 2 + 1];
    union { unsigned short u[8]; uint4 v; } p;
    p.u[0] = bf16rne(v0.x); p.u[1] = bf16rne(v0.y);
    p.u[2] = bf16rne(v0.z); p.u[3] = bf16rne(v0.w);
    p.u[4] = bf16rne(v1.x); p.u[5] = bf16rne(v1.y);
    p.u[6] = bf16rne(v1.z); p.u[7] = bf16rne(v1.w);
    ((uint4*)hb)[i] = p.v;
}

// ---------------------------------------------------------------------------
// CSR build: histogram -> exclusive scan -> rank (inverse permutation)
// ---------------------------------------------------------------------------
__global__ void hist_kernel(const int* __restrict__ eidx, unsigned* __restrict__ deg, int E) {
    int e = blockIdx.x * 256 + threadIdx.x;
    if (e < E) atomicAdd(deg + eidx[E + e], 1u);
}

__device__ __forceinline__ unsigned block_excl_scan_256(unsigned v, int tid,
                                                        unsigned* wsum, unsigned* wpre,
                                                        unsigned* total) {
    int lane = tid & 63, w = tid >> 6;
    unsigned inc = v;
#pragma unroll
    for (int o = 1; o < 64; o <<= 1) {
        unsigned t = __shfl_up(inc, o, 64);
        if (lane >= o) inc += t;
    }
    if (lane == 63) wsum[w] = inc;
    __syncthreads();
    if (tid == 0) {
        unsigned s = 0;
#pragma unroll
        for (int k = 0; k < 4; ++k) { wpre[k] = s; s += wsum[k]; }
        *total = s;
    }
    __syncthreads();
    return inc - v + wpre[w];
}

__global__ void scan_block_kernel(const unsigned* __restrict__ deg,
                                  unsigned* __restrict__ scanned,
                                  unsigned* __restrict__ blocksum, int N) {
    __shared__ unsigned wsum[4], wpre[4], total;
    int tid = threadIdx.x;
    int i = blockIdx.x * 256 + tid;
    unsigned v = (i < N) ? deg[i] : 0u;
    unsigned excl = block_excl_scan_256(v, tid, wsum, wpre, &total);
    if (i < N) scanned[i] = excl;
    if (tid == 0) blocksum[blockIdx.x] = total;
}

__global__ void scan_sums_kernel(const unsigned* __restrict__ blocksum,
                                 unsigned* __restrict__ blockpref, int NB) {
    __shared__ unsigned wsum[4], wpre[4], total;
    int tid = threadIdx.x;
    unsigned v = (tid < NB) ? blocksum[tid] : 0u;
    unsigned excl = block_excl_scan_256(v, tid, wsum, wpre, &total);
    if (tid < NB) blockpref[tid] = excl;
}

__global__ void scan_finalize_kernel(const unsigned* __restrict__ scanned,
                                     const unsigned* __restrict__ blockpref,
                                     unsigned* __restrict__ offsets,
                                     unsigned* __restrict__ cursor, int N, int E) {
    int i = blockIdx.x * 256 + threadIdx.x;
    if (i < N) {
        unsigned o = scanned[i] + blockpref[i >> 8];
        offsets[i] = o;
        cursor[i]  = o;
    }
    if (i == 0) offsets[N] = (unsigned)E;
}

__global__ void scatter_kernel(const int* __restrict__ eidx,
                               unsigned* __restrict__ cursor,
                               unsigned* __restrict__ rank, int E) {
    int e = blockIdx.x * 256 + threadIdx.x;
    if (e < E) {
        int d = eidx[E + e];
        rank[e] = atomicAdd(cursor + d, 1u);
    }
}

// ---------------------------------------------------------------------------
// Pass B: per-edge GEMM + activation -> bf16 msg at CSR position rank[e].
// Block = 256 = 4 waves; wave handles 32 edges (mt=2). No LDS, no barriers.
// ---------------------------------------------------------------------------
__global__ __launch_bounds__(256, 3)
void gemm_msg_kernel(const unsigned short* __restrict__ hb,
                     const int*   __restrict__ eidx,
                     const float* __restrict__ ea,
                     const unsigned short* __restrict__ bpack,
                     const float* __restrict__ be,
                     const float* __restrict__ bn,
                     const unsigned* __restrict__ rank,
                     unsigned short* __restrict__ msg,
                     int E) {
    const int tid  = threadIdx.x;
    const int wave = tid >> 6, lane = tid & 63;
    const int m    = lane & 15;
    const int quad = lane >> 4;
    const int base = blockIdx.x * 128 + wave * 32;

    const unsigned short* hsq[2];
    const unsigned short* hdq[2];
    const float*          epq[2];
#pragma unroll
    for (int mt = 0; mt < 2; ++mt) {
        int e  = base + mt * 16 + m;
        int eg = (e < E) ? e : (E - 1);
        int src = eidx[eg];
        int dst = eidx[E + eg];
        hsq[mt] = hb + (size_t)src * NODE_DIM + quad * 8;
        hdq[mt] = hb + (size_t)dst * NODE_DIM + quad * 8;
        epq[mt] = ea + (size_t)eg  * EDGE_DIM + quad * 8;
    }
    const unsigned short* bl = bpack + lane * 8;

    f32x4 acc[2][NT_TILES];
#pragma unroll
    for (int mt = 0; mt < 2; ++mt)
#pragma unroll
        for (int nt = 0; nt < NT_TILES; ++nt) acc[mt][nt] = (f32x4){0.f, 0.f, 0.f, 0.f};

#pragma unroll
    for (int kt = 0; kt < KT_TILES; ++kt) {
        bf16x8 A[2];
#pragma unroll
        for (int mt = 0; mt < 2; ++mt) {
            if (kt < 3) {
                A[mt] = *(const bf16x8*)(hsq[mt] + kt * 32);
            } else if (kt < 6) {
                A[mt] = *(const bf16x8*)(hdq[mt] + (kt - 3) * 32);
            } else {
                const float4 v0 = *(const float4*)(epq[mt] + (kt - 6) * 32);
                const float4 v1 = *(const float4*)(epq[mt] + (kt - 6) * 32 + 4);
                union { unsigned short u[8]; bf16x8 b; } t;
                t.u[0] = bf16rne(v0.x); t.u[1] = bf16rne(v0.y);
                t.u[2] = bf16rne(v0.z); t.u[3] = bf16rne(v0.w);
                t.u[4] = bf16rne(v1.x); t.u[5] = bf16rne(v1.y);
                t.u[6] = bf16rne(v1.z); t.u[7] = bf16rne(v1.w);
                A[mt] = t.b;
            }
        }
#pragma unroll
        for (int nt = 0; nt < NT_TILES; ++nt) {
            bf16x8 bfrag = *(const bf16x8*)(bl + (kt * NT_TILES + nt) * 512);
            acc[0][nt] = __builtin_amdgcn_mfma_f32_16x16x32_bf16(A[0], bfrag, acc[0][nt], 0, 0, 0);
            acc[1][nt] = __builtin_amdgcn_mfma_f32_16x16x32_bf16(A[1], bfrag, acc[1][nt], 0, 0, 0);
        }
    }

    // epilogue: C layout col = nt*16 + m, row-in-tile = quad*4 + r
#pragma unroll
    for (int mt = 0; mt < 2; ++mt) {
#pragma unroll
        for (int r = 0; r < 4; ++r) {
            const int ee = base + mt * 16 + quad * 4 + r;
            if (ee >= E) continue;
            const size_t prow = (size_t)rank[ee] * NODE_DIM;
#pragma unroll
            for (int nt = 0; nt < 6; ++nt) {
                const int col = nt * 16 + m;
                float g  = acc[mt][nt][r]     + be[col];
                float mm = acc[mt][nt + 6][r] + bn[col];
                float gate = 1.0f / (1.0f + __expf(-g));
                float sp   = fmaxf(mm, 0.0f) + __logf(1.0f + __expf(-fabsf(mm)));
                msg[prow + col] = bf16rne(gate * sp);
            }
        }
    }
}

// ---------------------------------------------------------------------------
// Pass C: streaming CSR reduce. Thread = (node, 8-col group): 12 threads/node,
// 16B loads, rows contiguous at offsets[n]..offsets[n+1].
// ---------------------------------------------------------------------------
__global__ __launch_bounds__(256)
void aggregate_kernel(const float* __restrict__ h,
                      const unsigned* __restrict__ offsets,
                      const unsigned short* __restrict__ msg,
                      float* __restrict__ out, int N) {
    int t = blockIdx.x * 256 + threadIdx.x;
    int n = t / 12, g = t % 12;
    if (n >= N) return;

    const unsigned o0 = offsets[n];
    const unsigned o1 = offsets[n + 1];
    const int deg = (int)(o1 - o0);

    float s0 = 0.f, s1 = 0.f, s2 = 0.f, s3 = 0.f;
    float s4 = 0.f, s5 = 0.f, s6 = 0.f, s7 = 0.f;
    for (unsigned k = o0; k < o1; ++k) {
        const uint4 v = *(const uint4*)(msg + (size_t)k * NODE_DIM + g * 8);
        s0 += __uint_as_float((v.x & 0xFFFFu) << 16);
        s1 += __uint_as_float(v.x & 0xFFFF0000u);
        s2 += __uint_as_float((v.y & 0xFFFFu) << 16);
        s3 += __uint_as_float(v.y & 0xFFFF0000u);
        s4 += __uint_as_float((v.z & 0xFFFFu) << 16);
        s5 += __uint_as_float(v.z & 0xFFFF0000u);
        s6 += __uint_as_float((v.w & 0xFFFFu) << 16);
        s7 += __uint_as_float(v.w & 0xFFFF0000u);
    }
    const float inv = 1.0f / (float)((deg > 0) ? deg : 1);
    const size_t basei = (size_t)n * NODE_DIM + g * 8;
    const float4 h0 = *(const float4*)(h + basei);
    const float4 h1 = *(const float4*)(h + basei + 4);
    float4 o0v = {h0.x + s0 * inv, h0.y + s1 * inv, h0.z + s2 * inv, h0.w + s3 * inv};
    float4 o1v = {h1.x + s4 * inv, h1.y + s5 * inv, h1.z + s6 * inv, h1.w + s7 * inv};
    *(float4*)(out + basei)     = o0v;
    *(float4*)(out + basei + 4) = o1v;
}

// ---------------------------------------------------------------------------
// Fallback (atomic path) if workspace is too small for the CSR pipeline.
// ---------------------------------------------------------------------------
#define TILE_E 64
__global__ __launch_bounds__(256, 4)
void cgconv_atomic_kernel(const float* __restrict__ h,
                          const int*   __restrict__ eidx,
                          const float* __restrict__ ea,
                          const unsigned short* __restrict__ bpack,
                          const float* __restrict__ be,
                          const float* __restrict__ bn,
                          float* __restrict__ hnew,
                          float* __restrict__ cnt,
                          int E) {
    const int tid  = threadIdx.x;
    const int wave = tid >> 6, lane = tid & 63;
    const int m    = lane & 15;
    const int quad = lane >> 4;

    const int e  = blockIdx.x * TILE_E + wave * 16 + m;
    const int eg = (e < E) ? e : (E - 1);
    const int src = eidx[eg];
    const int dst = eidx[E + eg];
    if (quad == 0 && e < E) unsafeAtomicAdd(cnt + dst, 1.0f);

    f32x4 acc[NT_TILES];
#pragma unroll
    for (int nt = 0; nt < NT_TILES; ++nt) acc[nt] = (f32x4){0.f, 0.f, 0.f, 0.f};

    const float* hsrc = h + (size_t)src * NODE_DIM;
    const float* hdst = h + (size_t)dst * NODE_DIM;
    const float* earo = ea + (size_t)eg * EDGE_DIM;

#pragma unroll
    for (int kt = 0; kt < KT_TILES; ++kt) {
        const int ko = kt * 32 + quad * 8;
        const float* p;
        if (kt < 3)      p = hsrc + ko;
        else if (kt < 6) p = hdst + (ko - NODE_DIM);
        else             p = earo + (ko - 2 * NODE_DIM);
        const float4 v0 = *(const float4*)p;
        const float4 v1 = *(const float4*)(p + 4);
        union { unsigned short u[8]; bf16x8 b; } A;
        A.u[0] = bf16rne(v0.x); A.u[1] = bf16rne(v0.y);
        A.u[2] = bf16rne(v0.z); A.u[3] = bf16rne(v0.w);
        A.u[4] = bf16rne(v1.x); A.u[5] = bf16rne(v1.y);
        A.u[6] = bf16rne(v1.z); A.u[7] = bf16rne(v1.w);
#pragma unroll
        for (int nt = 0; nt < NT_TILES; ++nt) {
            bf16x8 bfrag = *(const bf16x8*)(bpack +
                             (size_t)((kt * NT_TILES + nt) * 64 + lane) * 8);
            acc[nt] = __builtin_amdgcn_mfma_f32_16x16x32_bf16(A.b, bfrag, acc[nt], 0, 0, 0);
        }
    }

    int drow[4], erow[4];
#pragma unroll
    for (int r = 0; r < 4; ++r) {
        drow[r] = __shfl(dst, quad * 4 + r, 64);
        erow[r] = blockIdx.x * TILE_E + wave * 16 + quad * 4 + r;
    }
#pragma unroll
    for (int nt = 0; nt < 6; ++nt) {
        const int col = nt * 16 + m;
        const float bev = be[col];
        const float bnv = bn[col];
#pragma unroll
        for (int r = 0; r < 4; ++r) {
            if (erow[r] >= E) continue;
            float g  = acc[nt][r] + bev;
            float mm = acc[nt + 6][r] + bnv;
            float gate = 1.0f / (1.0f + __expf(-g));
            float sp   = fmaxf(mm, 0.0f) + __logf(1.0f + __expf(-fabsf(mm)));
            unsafeAtomicAdd(hnew + (size_t)drow[r] * NODE_DIM + col, gate * sp);
        }
    }
}

__global__ void finalize_kernel(const float* __restrict__ h,
                                const float* __restrict__ hnew,
                                const float* __restrict__ cnt,
                                float* __restrict__ out,
                                int total4) {
    int i = blockIdx.x * blockDim.x + threadIdx.x;
    if (i >= total4) return;
    int n = i / 24;
    float inv = 1.0f / fmaxf(cnt[n], 1.0f);
    float4 hv = ((const float4*)h)[i];
    float4 av = ((const float4*)hnew)[i];
    float4 o = {hv.x + av.x * inv, hv.y + av.y * inv, hv.z + av.z * inv, hv.w + av.w * inv};
    ((float4*)out)[i] = o;
}

// ---------------------------------------------------------------------------
extern "C" void kernel_launch(void* const* d_in, const int* in_sizes, int n_in,
                              void* d_out, int out_size, void* d_ws, size_t ws_size,
                              hipStream_t stream) {
    const float* h   = (const float*)d_in[0];
    const int*   ei  = (const int*)  d_in[1];
    const float* ea  = (const float*)d_in[2];
    const float* We  = (const float*)d_in[3];
    const float* be  = (const float*)d_in[4];
    const float* Wn  = (const float*)d_in[5];
    const float* bn  = (const float*)d_in[6];

    const int N = in_sizes[0] / NODE_DIM;     // 50000
    const int E = in_sizes[2] / EDGE_DIM;     // 800000
    char* ws = (char*)d_ws;

    size_t off = 0;
    auto take = [&](size_t bytes) { size_t o = off; off = (off + bytes + 511) & ~(size_t)511; return o; };
    const size_t O_BPACK  = take((size_t)KT_TILES * NT_TILES * 64 * 16);   // 96 KB
    const size_t O_DEG    = take((size_t)N * 4);
    const size_t O_SCAN   = take((size_t)N * 4);
    const size_t O_BSUM   = take(1024);
    const size_t O_BPREF  = take(1024);
    const size_t O_OFFS   = take((size_t)(N + 1) * 4);
    const size_t O_CURS   = take((size_t)N * 4);
    const size_t O_RANK   = take((size_t)E * 4);
    const size_t O_HB     = take((size_t)N * NODE_DIM * 2);               // 9.6 MB
    const size_t O_MSG    = take((size_t)E * NODE_DIM * 2);               // 153.6 MB
    const size_t NEED = off;

    unsigned short* bpack = (unsigned short*)(ws + O_BPACK);
    pack_w_kernel<<<(KT_TILES * NT_TILES * 64 + 255) / 256, 256, 0, stream>>>(We, Wn, bpack);

    if (ws_size >= NEED) {
        unsigned* deg    = (unsigned*)(ws + O_DEG);
        unsigned* scn    = (unsigned*)(ws + O_SCAN);
        unsigned* bsum   = (unsigned*)(ws + O_BSUM);
        unsigned* bpref  = (unsigned*)(ws + O_BPREF);
        unsigned* offs   = (unsigned*)(ws + O_OFFS);
        unsigned* curs   = (unsigned*)(ws + O_CURS);
        unsigned* rank   = (unsigned*)(ws + O_RANK);
        unsigned short* hb  = (unsigned short*)(ws + O_HB);
        unsigned short* msg = (unsigned short*)(ws + O_MSG);

        hipMemsetAsync(deg, 0, (size_t)N * 4, stream);

        const int total8 = N * NODE_DIM / 8;   // 600000
        cvt_h_kernel<<<(total8 + 255) / 256, 256, 0, stream>>>(h, hb, total8);

        const int NB = (N + 255) / 256;
        hist_kernel<<<(E + 255) / 256, 256, 0, stream>>>(ei, deg, E);
        scan_block_kernel<<<NB, 256, 0, stream>>>(deg, scn, bsum, N);
        scan_sums_kernel<<<1, 256, 0, stream>>>(bsum, bpref, NB);
        scan_finalize_kernel<<<NB, 256, 0, stream>>>(scn, bpref, offs, curs, N, E);
        scatter_kernel<<<(E + 255) / 256, 256, 0, stream>>>(ei, curs, rank, E);

        gemm_msg_kernel<<<(E + 127) / 128, 256, 0, stream>>>(hb, ei, ea, bpack, be, bn, rank, msg, E);

        const int aggthreads = N * 12;
        aggregate_kernel<<<(aggthreads + 255) / 256, 256, 0, stream>>>(h, offs, msg, (float*)d_out, N);
    } else {
        size_t cnt_off  = O_DEG;
        size_t hnew_off = (cnt_off + (size_t)N * 4 + 511) & ~(size_t)511;
        float* cnt  = (float*)(ws + cnt_off);
        float* hnew = (float*)(ws + hnew_off);
        hipMemsetAsync(ws + cnt_off, 0, hnew_off - cnt_off + (size_t)N * NODE_DIM * 4, stream);
        cgconv_atomic_kernel<<<(E + TILE_E - 1) / TILE_E, 256, 0, stream>>>(
            h, ei, ea, bpack, be, bn, hnew, cnt, E);
        const int total4 = N * (NODE_DIM / 4);
        finalize_kernel<<<(total4 + 255) / 256, 256, 0, stream>>>(h, hnew, cnt, (float*)d_out, total4);
    }
}